// Round 9
// baseline (419.362 us; speedup 1.0000x reference)
//
#include <hip/hip_runtime.h>
#include <math.h>

#define BB 1024
#define TT 25
#define LP 10
#define MAXD 11

// conv2/conv3 spike staging: rows 0..24 = spikes, row 25 = zeros
#define XR2 26
#define XC 264            // 256 ch + 8 pad, 16B-aligned rows
#define XSZ2 (XR2 * XC)

// conv1 staging: 160 padded channels + 8 pad
#define IC1 140
#define ICP1 160
#define XC1 168
#define XSZ1 (XR2 * XC1)      // per batch, per split: 26*168 = 4368
#define SS1 (2 * XSZ1)        // per-split stride (2 batches) = 8736

typedef __bf16 bf16x8 __attribute__((ext_vector_type(8)));
typedef float  f32x4  __attribute__((ext_vector_type(4)));

#define MFMA16(A, B, C) __builtin_amdgcn_mfma_f32_16x16x32_bf16((A), (B), (C), 0, 0, 0)

// ---------------------------------------------------------------------------
// Triple-split bf16 DCLS taps: K == Khi + Kmid + Klo EXACTLY (Dekker splits).
// Layout [j][Opad][Ipad]; rows o>=O and cols i>=I are zero.
// ---------------------------------------------------------------------------
__global__ void gen_trip(const float* __restrict__ W,
                         const float* __restrict__ P,
                         const float* __restrict__ SIG,
                         __bf16* __restrict__ Khi, __bf16* __restrict__ Kmid,
                         __bf16* __restrict__ Klo,
                         int O, int Opad, int I, int Ipad) {
    int idx = blockIdx.x * blockDim.x + threadIdx.x;
    if (idx >= Opad * Ipad) return;
    int i = idx % Ipad;
    int o = idx / Ipad;
    if (o >= O || i >= I) {
#pragma unroll
        for (int j = 0; j < MAXD; ++j) {
            size_t ofs = ((size_t)(j * Opad + o)) * Ipad + i;
            Khi[ofs] = (__bf16)0.0f;
            Kmid[ofs] = (__bf16)0.0f;
            Klo[ofs] = (__bf16)0.0f;
        }
        return;
    }
    int widx = o * I + i;
    float w  = W[widx];
    float pc = P[widx] + (float)(MAXD / 2);
    float s  = fabsf(SIG[widx]) + 0.27f;
    float x[MAXD];
    float sum = 0.f;
#pragma unroll
    for (int j = 0; j < MAXD; ++j) {
        float d = ((float)j - pc) / s;
        x[j] = expf(-0.5f * d * d);
        sum += x[j];
    }
    float denom = sum + 1e-7f;
#pragma unroll
    for (int j = 0; j < MAXD; ++j) {
        float kv = w * (x[j] / denom);
        __bf16 h = (__bf16)kv;
        float  r1 = kv - (float)h;
        __bf16 m = (__bf16)r1;
        float  r2 = r1 - (float)m;
        __bf16 l = (__bf16)r2;
        size_t ofs = ((size_t)(j * Opad + o)) * Ipad + i;
        Khi[ofs] = h;
        Kmid[ofs] = m;
        Klo[ofs] = l;
    }
}

// ---------------------------------------------------------------------------
// Layer 1 (MFMA, exact 6-term split): r9 2-batch form, verbatim (~150us,
// 57% of the 16x16 MFMA ceiling — note: its MFMA order has same-acc gap 8).
// ---------------------------------------------------------------------------
__global__ __launch_bounds__(512, 2)
void conv1_mfma(const float* __restrict__ xin,     // (B, T, 140)
                const __bf16* __restrict__ Khi,    // [j][256][160]
                const __bf16* __restrict__ Kmid,
                const __bf16* __restrict__ Klo,
                const float* __restrict__ bias,
                const float* __restrict__ gamma,
                const float* __restrict__ beta,
                const float* __restrict__ mean,
                const float* __restrict__ var,
                __bf16* __restrict__ spk1) {
    __shared__ __align__(16) char smem[3 * SS1 * 2];   // 52416 B; ys needs 27648
    __bf16* xs = (__bf16*)smem;                        // [split][bl][26][168]
    float*  ys = (float*)smem;                         // [256][27] per-batch

    const int rr = blockIdx.x & 7;
    const int gg = blockIdx.x >> 3;
    const int pp = 2 * (rr + 8 * (gg >> 1)) + (gg & 1);
    const int b0 = pp * 2;

    const int tid  = threadIdx.x;
    const int w    = tid >> 6;
    const int lane = tid & 63;
    const int lm   = lane & 15;
    const int quad = lane >> 4;

    {
        uint32_t* xz = (uint32_t*)smem;
        for (int k = tid; k < 3 * SS1 / 2; k += 512) xz[k] = 0u;
    }
    __syncthreads();
#pragma unroll
    for (int bl = 0; bl < 2; ++bl) {
        const float* src = xin + (size_t)(b0 + bl) * (TT * IC1);
        for (int k = tid; k < TT * IC1; k += 512) {
            int t = k / IC1;
            int i = k - t * IC1;
            float x  = src[k];
            __bf16 h = (__bf16)x;
            float r1 = x - (float)h;
            __bf16 m = (__bf16)r1;
            float r2 = r1 - (float)m;
            __bf16 l = (__bf16)r2;
            int ofs = bl * XSZ1 + t * XC1 + i;
            xs[0 * SS1 + ofs] = h;
            xs[1 * SS1 + ofs] = m;
            xs[2 * SS1 + ofs] = l;
        }
    }
    __syncthreads();

    f32x4 acc[2][4];   // [p][bl*2+th]
#pragma unroll
    for (int p = 0; p < 2; ++p)
#pragma unroll
        for (int nt = 0; nt < 4; ++nt) acc[p][nt] = (f32x4){0.f, 0.f, 0.f, 0.f};

    auto loadA = [&](int n, bf16x8* Ah, bf16x8* Am, bf16x8* Al) {
        n = (n > 54) ? 54 : n;
        const int j = n / 5;
        const int ic = n - 5 * j;
        const size_t base =
            (size_t)(j * 256 + w * 32 + lm) * ICP1 + ic * 32 + quad * 8;
#pragma unroll
        for (int p = 0; p < 2; ++p) {
            Ah[p] = *(const bf16x8*)(Khi  + base + p * 16 * ICP1);
            Am[p] = *(const bf16x8*)(Kmid + base + p * 16 * ICP1);
            Al[p] = *(const bf16x8*)(Klo  + base + p * 16 * ICP1);
        }
    };

    auto step = [&](int n, bf16x8* Ah, bf16x8* Am, bf16x8* Al) {
        const int j = n / 5;
        const int ic = n - 5 * j;
        int r0 = lm + j - 10;          r0 = ((unsigned)r0 < 25u) ? r0 : 25;
        int r1 = 16 + lm + j - 10;     r1 = ((unsigned)r1 < 25u) ? r1 : 25;
        const int col = ic * 32 + quad * 8;
#pragma unroll
        for (int bl = 0; bl < 2; ++bl) {
            bf16x8 Bh[2], Bm[2], Bl[2];
#pragma unroll
            for (int th = 0; th < 2; ++th) {
                const int row = th ? r1 : r0;
                const int ofs = bl * XSZ1 + row * XC1 + col;
                Bh[th] = *(const bf16x8*)&xs[0 * SS1 + ofs];
                Bm[th] = *(const bf16x8*)&xs[1 * SS1 + ofs];
                Bl[th] = *(const bf16x8*)&xs[2 * SS1 + ofs];
            }
#pragma unroll
            for (int p = 0; p < 2; ++p)
#pragma unroll
                for (int th = 0; th < 2; ++th)
                    acc[p][bl * 2 + th] = MFMA16(Ah[p], Bh[th], acc[p][bl * 2 + th]);
#pragma unroll
            for (int p = 0; p < 2; ++p)
#pragma unroll
                for (int th = 0; th < 2; ++th)
                    acc[p][bl * 2 + th] = MFMA16(Ah[p], Bm[th], acc[p][bl * 2 + th]);
#pragma unroll
            for (int p = 0; p < 2; ++p)
#pragma unroll
                for (int th = 0; th < 2; ++th)
                    acc[p][bl * 2 + th] = MFMA16(Am[p], Bh[th], acc[p][bl * 2 + th]);
#pragma unroll
            for (int p = 0; p < 2; ++p)
#pragma unroll
                for (int th = 0; th < 2; ++th)
                    acc[p][bl * 2 + th] = MFMA16(Ah[p], Bl[th], acc[p][bl * 2 + th]);
#pragma unroll
            for (int p = 0; p < 2; ++p)
#pragma unroll
                for (int th = 0; th < 2; ++th)
                    acc[p][bl * 2 + th] = MFMA16(Am[p], Bm[th], acc[p][bl * 2 + th]);
#pragma unroll
            for (int p = 0; p < 2; ++p)
#pragma unroll
                for (int th = 0; th < 2; ++th)
                    acc[p][bl * 2 + th] = MFMA16(Al[p], Bh[th], acc[p][bl * 2 + th]);
        }
    };

    bf16x8 A0h[2], A0m[2], A0l[2], A1h[2], A1m[2], A1l[2];
    loadA(0, A0h, A0m, A0l);
    for (int n = 0; n < 54; n += 2) {
        loadA(n + 1, A1h, A1m, A1l);
        step(n, A0h, A0m, A0l);
        loadA(n + 2, A0h, A0m, A0l);
        step(n + 1, A1h, A1m, A1l);
    }
    step(54, A0h, A0m, A0l);

#pragma unroll
    for (int bl = 0; bl < 2; ++bl) {
        __syncthreads();
#pragma unroll
        for (int p = 0; p < 2; ++p)
#pragma unroll
            for (int th = 0; th < 2; ++th) {
                int t = th * 16 + lm;
                if (t < TT) {
                    int ob = w * 32 + p * 16 + quad * 4;
#pragma unroll
                    for (int v = 0; v < 4; ++v)
                        ys[(ob + v) * 27 + t] = acc[p][bl * 2 + th][v];
                }
            }
        __syncthreads();
        if (tid < 256) {
            const int o = tid;
            float scale = gamma[o] / sqrtf(var[o] + 1e-5f);
            float ofs   = (bias[o] - mean[o]) * scale + beta[o];
            unsigned short* dst =
                (unsigned short*)spk1 + (size_t)(b0 + bl) * (TT * 256) + o;
            const float* yrow = &ys[o * 27];
            float memv = 0.f;
#pragma unroll
            for (int t = 0; t < TT; ++t) {
                float a     = yrow[t] * scale + ofs;
                float reset = (memv > 1.0f) ? 1.0f : 0.f;
                memv        = 0.95f * memv + a - reset;
                dst[t * 256] = (memv > 1.0f) ? 0x3F80 : 0;
            }
        }
    }
}

// ---------------------------------------------------------------------------
// Layer 2 — v9: v8 (168us, 45% occ, no spill) with the MFMA schedule widened
// to same-acc gap 8. v8's nt-pair-major order reused each accumulator after
// 4 issues (~19 cyc) — below the MFMA accumulate latency; conv1's gap-8
// order runs 57% of floor vs v8's 41%. Here B is kept live for a PAIR of
// batches (4 x bf16x8 = 16 VGPR) and each split-round rotates all 8 accs
// before any reuse. Budget: 64 acc + 24 A + 16 B + ~16 addr ~= 120 <= 128.
// Everything else (kg-split, batched-A, XCD-parity half, epilogue) = v8.
// ---------------------------------------------------------------------------
__attribute__((amdgpu_waves_per_eu(4, 4)))
__global__ __launch_bounds__(512)
void conv2_mfma(const __bf16* __restrict__ spk1,
                const __bf16* __restrict__ Khi,   // [j][256][256]
                const __bf16* __restrict__ Kmid,
                const __bf16* __restrict__ Klo,
                const float* __restrict__ bias,
                const float* __restrict__ gamma,
                const float* __restrict__ beta,
                const float* __restrict__ mean,
                const float* __restrict__ var,
                __bf16* __restrict__ spk2) {
    __shared__ __align__(16) char smem[68224];
    __bf16* xs  = (__bf16*)smem;                 // [4][26][264] = 54912 B
    float*  ysq = (float*)(smem + 54912);        // [2][64][26]  = 13312 B

    const int h    = blockIdx.x & 1;             // channel half (XCD-parity)
    const int bg   = blockIdx.x >> 1;            // batch group
    const int b0   = bg * 4;
    const int oc0  = h * 128;

    const int tid  = threadIdx.x;
    const int w    = tid >> 6;                   // 0..7
    const int wc   = w & 3;                      // channel tile (32 ch)
    const int kg   = w >> 2;                     // K-group 0/1
    const int lane = tid & 63;
    const int lm   = lane & 15;
    const int quad = lane >> 4;

    for (int k = tid; k < 4 * (XC / 2); k += 512) {
        int bl = k / (XC / 2);
        int c  = k % (XC / 2);
        ((uint32_t*)xs)[(bl * XSZ2 + 25 * XC) / 2 + c] = 0u;
    }
    for (int k = tid; k < 4 * 800; k += 512) {
        int bl = k / 800;
        int v  = k % 800;
        int t  = v >> 5;
        int iv = v & 31;
        uint4 d = ((const uint4*)(spk1 + (size_t)(b0 + bl) * (TT * 256)))[v];
        *(uint4*)&xs[bl * XSZ2 + t * XC + iv * 8] = d;
    }
    __syncthreads();

    f32x4 acc[2][8];   // [pi][bl*2+th]
#pragma unroll
    for (int pi = 0; pi < 2; ++pi)
#pragma unroll
        for (int nt = 0; nt < 8; ++nt) acc[pi][nt] = (f32x4){0.f, 0.f, 0.f, 0.f};

    {
        const int n0 = kg * 44;
#pragma unroll 1
        for (int n = n0; n < n0 + 44; ++n) {
            const int j = n >> 3, ic = n & 7;
            // ---- batched A group: 6 independent global loads, one wait ----
            const size_t base =
                (size_t)(j * 256 + oc0 + wc * 32 + lm) * 256 + ic * 32 + quad * 8;
            bf16x8 Ah0 = *(const bf16x8*)(Khi  + base);
            bf16x8 Ah1 = *(const bf16x8*)(Khi  + base + 16 * 256);
            bf16x8 Am0 = *(const bf16x8*)(Kmid + base);
            bf16x8 Am1 = *(const bf16x8*)(Kmid + base + 16 * 256);
            bf16x8 Al0 = *(const bf16x8*)(Klo  + base);
            bf16x8 Al1 = *(const bf16x8*)(Klo  + base + 16 * 256);
            int r0 = lm + j - 10;          r0 = ((unsigned)r0 < 25u) ? r0 : 25;
            int r1 = 16 + lm + j - 10;     r1 = ((unsigned)r1 < 25u) ? r1 : 25;
            const int col = ic * 32 + quad * 8;
            // ---- bl-pair B (4 live fragments): same-acc gap = 8 ----------
#pragma unroll
            for (int bp = 0; bp < 2; ++bp) {
                const int blA = bp * 2, blB = bp * 2 + 1;
                bf16x8 B0A = *(const bf16x8*)&xs[blA * XSZ2 + r0 * XC + col];
                bf16x8 B1A = *(const bf16x8*)&xs[blA * XSZ2 + r1 * XC + col];
                bf16x8 B0B = *(const bf16x8*)&xs[blB * XSZ2 + r0 * XC + col];
                bf16x8 B1B = *(const bf16x8*)&xs[blB * XSZ2 + r1 * XC + col];
                const int a0 = blA * 2, a1 = blA * 2 + 1;
                const int a2 = blB * 2, a3 = blB * 2 + 1;
                // round Ah: rotate all 8 accs
                acc[0][a0] = MFMA16(Ah0, B0A, acc[0][a0]);
                acc[1][a0] = MFMA16(Ah1, B0A, acc[1][a0]);
                acc[0][a1] = MFMA16(Ah0, B1A, acc[0][a1]);
                acc[1][a1] = MFMA16(Ah1, B1A, acc[1][a1]);
                acc[0][a2] = MFMA16(Ah0, B0B, acc[0][a2]);
                acc[1][a2] = MFMA16(Ah1, B0B, acc[1][a2]);
                acc[0][a3] = MFMA16(Ah0, B1B, acc[0][a3]);
                acc[1][a3] = MFMA16(Ah1, B1B, acc[1][a3]);
                // round Am
                acc[0][a0] = MFMA16(Am0, B0A, acc[0][a0]);
                acc[1][a0] = MFMA16(Am1, B0A, acc[1][a0]);
                acc[0][a1] = MFMA16(Am0, B1A, acc[0][a1]);
                acc[1][a1] = MFMA16(Am1, B1A, acc[1][a1]);
                acc[0][a2] = MFMA16(Am0, B0B, acc[0][a2]);
                acc[1][a2] = MFMA16(Am1, B0B, acc[1][a2]);
                acc[0][a3] = MFMA16(Am0, B1B, acc[0][a3]);
                acc[1][a3] = MFMA16(Am1, B1B, acc[1][a3]);
                // round Al
                acc[0][a0] = MFMA16(Al0, B0A, acc[0][a0]);
                acc[1][a0] = MFMA16(Al1, B0A, acc[1][a0]);
                acc[0][a1] = MFMA16(Al0, B1A, acc[0][a1]);
                acc[1][a1] = MFMA16(Al1, B1A, acc[1][a1]);
                acc[0][a2] = MFMA16(Al0, B0B, acc[0][a2]);
                acc[1][a2] = MFMA16(Al1, B0B, acc[1][a2]);
                acc[0][a3] = MFMA16(Al0, B1B, acc[0][a3]);
                acc[1][a3] = MFMA16(Al1, B1B, acc[1][a3]);
            }
        }
    }

    // ------- epilogue: combine K-groups, BN + LIF, spikes to global -------
    // 64-ch chunk q of this block's 128: owner waves wc in {2q,2q+1}, both kg.
#pragma unroll
    for (int bl = 0; bl < 4; ++bl) {
#pragma unroll
        for (int q = 0; q < 2; ++q) {
            __syncthreads();
            if ((wc >> 1) == q) {
#pragma unroll
                for (int pi = 0; pi < 2; ++pi)
#pragma unroll
                    for (int th = 0; th < 2; ++th) {
                        int t = th * 16 + lm;
                        if (t < TT) {
                            int ol = (wc & 1) * 32 + pi * 16 + quad * 4;
#pragma unroll
                            for (int v = 0; v < 4; ++v)
                                ysq[(kg * 64 + ol + v) * 26 + t] =
                                    acc[pi][bl * 2 + th][v];
                        }
                    }
            }
            __syncthreads();
            if (tid < 64) {
                const int o = oc0 + q * 64 + tid;
                float scale = gamma[o] / sqrtf(var[o] + 1e-5f);
                float ofs   = (bias[o] - mean[o]) * scale + beta[o];
                const float* yr0 = &ysq[tid * 26];
                const float* yr1 = &ysq[(64 + tid) * 26];
                unsigned short* dst =
                    (unsigned short*)spk2 + (size_t)(b0 + bl) * (TT * 256) + o;
                float memv = 0.f;
#pragma unroll
                for (int t = 0; t < TT; ++t) {
                    float a     = (yr0[t] + yr1[t]) * scale + ofs;
                    float reset = (memv > 1.0f) ? 1.0f : 0.f;
                    memv        = 0.95f * memv + a - reset;
                    dst[t * 256] = (memv > 1.0f) ? 0x3F80 : 0;
                }
            }
        }
    }
}

// ---------------------------------------------------------------------------
// Layer 3 + LIF3: staging spk2 from global (A3 = 528 KB, L2-resident).
// Grid 256 x 4 batches, 512 threads. Verbatim from r4.
// ---------------------------------------------------------------------------
__global__ __launch_bounds__(512, 2)
void conv3_mfma(const __bf16* __restrict__ spk2,
                const __bf16* __restrict__ K3hi,   // [j][32][256]
                const __bf16* __restrict__ K3mid,
                const __bf16* __restrict__ K3lo,
                const float* __restrict__ b3,
                float* __restrict__ out) {
    __shared__ __align__(16) char smem[54912];
    __bf16* xs  = (__bf16*)smem;                 // [4][26][264] = 54912 B
    float*  ys3 = (float*)smem;                  // [4][32][26] alias (after)

    const int b0   = blockIdx.x * 4;
    const int tid  = threadIdx.x;
    const int w    = tid >> 6;                   // 0..7
    const int lane = tid & 63;
    const int lm   = lane & 15;
    const int quad = lane >> 4;

    for (int k = tid; k < 4 * (XC / 2); k += 512) {
        int bl = k / (XC / 2);
        int c  = k % (XC / 2);
        ((uint32_t*)xs)[(bl * XSZ2 + 25 * XC) / 2 + c] = 0u;
    }
    for (int k = tid; k < 4 * 800; k += 512) {
        int bl = k / 800;
        int v  = k % 800;
        int t  = v >> 5;
        int iv = v & 31;
        uint4 d = ((const uint4*)(spk2 + (size_t)(b0 + bl) * (TT * 256)))[v];
        *(uint4*)&xs[bl * XSZ2 + t * XC + iv * 8] = d;
    }
    __syncthreads();

    {
        const int p3  = w >> 2;      // o3-tile (0..1)
        const int bl3 = w & 3;       // batch (0..3)
        f32x4 accH[2], accM[2], accL[2];   // [th]
#pragma unroll
        for (int th = 0; th < 2; ++th) {
            accH[th] = (f32x4){0.f, 0.f, 0.f, 0.f};
            accM[th] = (f32x4){0.f, 0.f, 0.f, 0.f};
            accL[th] = (f32x4){0.f, 0.f, 0.f, 0.f};
        }

        auto loadA3 = [&](int n, bf16x8* Ah, bf16x8* Am, bf16x8* Al) {
            n = (n > 87) ? 87 : n;
            const int j = n >> 3, ic = n & 7;
            const size_t kofs =
                ((size_t)(j * 32 + p3 * 16 + lm)) * 256 + ic * 32 + quad * 8;
            *Ah = *(const bf16x8*)(K3hi  + kofs);
            *Am = *(const bf16x8*)(K3mid + kofs);
            *Al = *(const bf16x8*)(K3lo  + kofs);
        };
        auto step3 = [&](int n, bf16x8 Ah, bf16x8 Am, bf16x8 Al) {
            const int j = n >> 3, ic = n & 7;
#pragma unroll
            for (int th = 0; th < 2; ++th) {
                int r = th * 16 + lm + j - 10;
                r = ((unsigned)r < 25u) ? r : 25;
                bf16x8 Bf =
                    *(const bf16x8*)&xs[bl3 * XSZ2 + r * XC + ic * 32 + quad * 8];
                accH[th] = MFMA16(Ah, Bf, accH[th]);
                accM[th] = MFMA16(Am, Bf, accM[th]);
                accL[th] = MFMA16(Al, Bf, accL[th]);
            }
        };

        bf16x8 A0h, A0m, A0l, A1h, A1m, A1l;
        loadA3(0, &A0h, &A0m, &A0l);
        for (int n = 0; n < 86; n += 2) {
            loadA3(n + 1, &A1h, &A1m, &A1l);
            step3(n, A0h, A0m, A0l);
            loadA3(n + 2, &A0h, &A0m, &A0l);
            step3(n + 1, A1h, A1m, A1l);
        }
        loadA3(87, &A1h, &A1m, &A1l);
        step3(86, A0h, A0m, A0l);
        step3(87, A1h, A1m, A1l);

        __syncthreads();   // xs dead; reuse smem as ys3
#pragma unroll
        for (int th = 0; th < 2; ++th) {
            int t = th * 16 + lm;
            if (t < TT) {
#pragma unroll
                for (int v = 0; v < 4; ++v)
                    ys3[(bl3 * 32 + p3 * 16 + quad * 4 + v) * 26 + t] =
                        accH[th][v] + accM[th][v] + accL[th][v];
            }
        }
        __syncthreads();

        if (tid < 80) {
            const int bl2 = tid / 20;
            const int o   = tid % 20;
            float memv = 0.f;
            float bo   = b3[o];
            const float* yrow = &ys3[(bl2 * 32 + o) * 26];
#pragma unroll
            for (int t = 0; t < TT; ++t) {
                float a     = yrow[t] + bo;
                float reset = (memv > 1.0f) ? 1.0f : 0.f;
                memv        = 0.95f * memv + a - reset;
                float spk   = (memv > 1.0f) ? 1.0f : 0.f;
                out[(t * BB + (b0 + bl2)) * 20 + o]               = spk;
                out[TT * BB * 20 + (t * BB + (b0 + bl2)) * 20 + o] = memv;
            }
        }
    }
}

// ---------------------------------------------------------------------------
extern "C" void kernel_launch(void* const* d_in, const int* in_sizes, int n_in,
                              void* d_out, int out_size, void* d_ws, size_t ws_size,
                              hipStream_t stream) {
    const float* data = (const float*)d_in[0];
    const float* W1   = (const float*)d_in[1];
    const float* b1   = (const float*)d_in[2];
    const float* P1   = (const float*)d_in[3];
    const float* SIG1 = (const float*)d_in[4];
    const float* g1   = (const float*)d_in[5];
    const float* be1  = (const float*)d_in[6];
    const float* m1   = (const float*)d_in[7];
    const float* v1   = (const float*)d_in[8];
    const float* W2   = (const float*)d_in[9];
    const float* b2   = (const float*)d_in[10];
    const float* P2   = (const float*)d_in[11];
    const float* SIG2 = (const float*)d_in[12];
    const float* g2   = (const float*)d_in[13];
    const float* be2  = (const float*)d_in[14];
    const float* m2   = (const float*)d_in[15];
    const float* v2   = (const float*)d_in[16];
    const float* W3   = (const float*)d_in[17];
    const float* b3   = (const float*)d_in[18];
    const float* P3   = (const float*)d_in[19];
    const float* SIG3 = (const float*)d_in[20];
    float* out = (float*)d_out;

    // workspace layout (byte offsets, all 16B-aligned)
    char* p = (char*)d_ws;
    __bf16* K1hi  = (__bf16*)p;  p += 901120;    // 11*256*160 bf16
    __bf16* K1mid = (__bf16*)p;  p += 901120;
    __bf16* K1lo  = (__bf16*)p;  p += 901120;
    __bf16* spk1  = (__bf16*)p;  p += 13107200;  // 1024*25*256 bf16
    __bf16* K2hi  = (__bf16*)p;  p += 1441792;   // 11*256*256 bf16
    __bf16* K2mid = (__bf16*)p;  p += 1441792;
    __bf16* K2lo  = (__bf16*)p;  p += 1441792;
    __bf16* K3hi  = (__bf16*)p;  p += 180224;    // 11*32*256 bf16
    __bf16* K3mid = (__bf16*)p;  p += 180224;
    __bf16* K3lo  = (__bf16*)p;  p += 180224;
    __bf16* spk2  = (__bf16*)p;                  // 1024*25*256 bf16 = 13107200

    gen_trip<<<(256 * 160 + 255) / 256, 256, 0, stream>>>(
        W1, P1, SIG1, K1hi, K1mid, K1lo, 256, 256, 140, 160);
    gen_trip<<<(256 * 256 + 255) / 256, 256, 0, stream>>>(
        W2, P2, SIG2, K2hi, K2mid, K2lo, 256, 256, 256, 256);
    gen_trip<<<(32 * 256 + 255) / 256, 256, 0, stream>>>(
        W3, P3, SIG3, K3hi, K3mid, K3lo, 20, 32, 256, 256);

    conv1_mfma<<<BB / 2, 512, 0, stream>>>(data, K1hi, K1mid, K1lo,
                                           b1, g1, be1, m1, v1, spk1);
    conv2_mfma<<<BB / 2, 512, 0, stream>>>(spk1, K2hi, K2mid, K2lo,
                                           b2, g2, be2, m2, v2, spk2);
    conv3_mfma<<<BB / 4, 512, 0, stream>>>(spk2, K3hi, K3mid, K3lo, b3, out);
}

// Round 10
// 400.967 us; speedup vs baseline: 1.0459x; 1.0459x over previous
//
#include <hip/hip_runtime.h>
#include <math.h>

#define BB 1024
#define TT 25
#define LP 10
#define MAXD 11

// conv2/conv3 spike staging: rows 0..24 = spikes, row 25 = zeros
#define XR2 26
#define XC 264            // 256 ch + 8 pad, 16B-aligned rows
#define XSZ2 (XR2 * XC)

// conv1 staging: 160 padded channels + 8 pad
#define IC1 140
#define ICP1 160
#define XC1 168
#define XSZ1 (XR2 * XC1)      // per batch, per split: 26*168 = 4368
#define SS1 (2 * XSZ1)        // per-split stride (2 batches) = 8736

typedef __bf16 bf16x8 __attribute__((ext_vector_type(8)));
typedef float  f32x4  __attribute__((ext_vector_type(4)));

#define MFMA16(A, B, C) __builtin_amdgcn_mfma_f32_16x16x32_bf16((A), (B), (C), 0, 0, 0)

// ---------------------------------------------------------------------------
// Triple-split bf16 DCLS taps: K == Khi + Kmid + Klo EXACTLY (Dekker splits).
// Layout [j][Opad][Ipad]; rows o>=O and cols i>=I are zero.
// ---------------------------------------------------------------------------
__global__ void gen_trip(const float* __restrict__ W,
                         const float* __restrict__ P,
                         const float* __restrict__ SIG,
                         __bf16* __restrict__ Khi, __bf16* __restrict__ Kmid,
                         __bf16* __restrict__ Klo,
                         int O, int Opad, int I, int Ipad) {
    int idx = blockIdx.x * blockDim.x + threadIdx.x;
    if (idx >= Opad * Ipad) return;
    int i = idx % Ipad;
    int o = idx / Ipad;
    if (o >= O || i >= I) {
#pragma unroll
        for (int j = 0; j < MAXD; ++j) {
            size_t ofs = ((size_t)(j * Opad + o)) * Ipad + i;
            Khi[ofs] = (__bf16)0.0f;
            Kmid[ofs] = (__bf16)0.0f;
            Klo[ofs] = (__bf16)0.0f;
        }
        return;
    }
    int widx = o * I + i;
    float w  = W[widx];
    float pc = P[widx] + (float)(MAXD / 2);
    float s  = fabsf(SIG[widx]) + 0.27f;
    float x[MAXD];
    float sum = 0.f;
#pragma unroll
    for (int j = 0; j < MAXD; ++j) {
        float d = ((float)j - pc) / s;
        x[j] = expf(-0.5f * d * d);
        sum += x[j];
    }
    float denom = sum + 1e-7f;
#pragma unroll
    for (int j = 0; j < MAXD; ++j) {
        float kv = w * (x[j] / denom);
        __bf16 h = (__bf16)kv;
        float  r1 = kv - (float)h;
        __bf16 m = (__bf16)r1;
        float  r2 = r1 - (float)m;
        __bf16 l = (__bf16)r2;
        size_t ofs = ((size_t)(j * Opad + o)) * Ipad + i;
        Khi[ofs] = h;
        Kmid[ofs] = m;
        Klo[ofs] = l;
    }
}

// ---------------------------------------------------------------------------
// Layer 1 (MFMA, exact 6-term split): r9 2-batch form, verbatim (~140-150us;
// sits at its dual A-BW + LDS-pipe cap ~53-57% of MFMA floor).
// ---------------------------------------------------------------------------
__global__ __launch_bounds__(512, 2)
void conv1_mfma(const float* __restrict__ xin,     // (B, T, 140)
                const __bf16* __restrict__ Khi,    // [j][256][160]
                const __bf16* __restrict__ Kmid,
                const __bf16* __restrict__ Klo,
                const float* __restrict__ bias,
                const float* __restrict__ gamma,
                const float* __restrict__ beta,
                const float* __restrict__ mean,
                const float* __restrict__ var,
                __bf16* __restrict__ spk1) {
    __shared__ __align__(16) char smem[3 * SS1 * 2];   // 52416 B; ys needs 27648
    __bf16* xs = (__bf16*)smem;                        // [split][bl][26][168]
    float*  ys = (float*)smem;                         // [256][27] per-batch

    const int rr = blockIdx.x & 7;
    const int gg = blockIdx.x >> 3;
    const int pp = 2 * (rr + 8 * (gg >> 1)) + (gg & 1);
    const int b0 = pp * 2;

    const int tid  = threadIdx.x;
    const int w    = tid >> 6;
    const int lane = tid & 63;
    const int lm   = lane & 15;
    const int quad = lane >> 4;

    {
        uint32_t* xz = (uint32_t*)smem;
        for (int k = tid; k < 3 * SS1 / 2; k += 512) xz[k] = 0u;
    }
    __syncthreads();
#pragma unroll
    for (int bl = 0; bl < 2; ++bl) {
        const float* src = xin + (size_t)(b0 + bl) * (TT * IC1);
        for (int k = tid; k < TT * IC1; k += 512) {
            int t = k / IC1;
            int i = k - t * IC1;
            float x  = src[k];
            __bf16 h = (__bf16)x;
            float r1 = x - (float)h;
            __bf16 m = (__bf16)r1;
            float r2 = r1 - (float)m;
            __bf16 l = (__bf16)r2;
            int ofs = bl * XSZ1 + t * XC1 + i;
            xs[0 * SS1 + ofs] = h;
            xs[1 * SS1 + ofs] = m;
            xs[2 * SS1 + ofs] = l;
        }
    }
    __syncthreads();

    f32x4 acc[2][4];   // [p][bl*2+th]
#pragma unroll
    for (int p = 0; p < 2; ++p)
#pragma unroll
        for (int nt = 0; nt < 4; ++nt) acc[p][nt] = (f32x4){0.f, 0.f, 0.f, 0.f};

    auto loadA = [&](int n, bf16x8* Ah, bf16x8* Am, bf16x8* Al) {
        n = (n > 54) ? 54 : n;
        const int j = n / 5;
        const int ic = n - 5 * j;
        const size_t base =
            (size_t)(j * 256 + w * 32 + lm) * ICP1 + ic * 32 + quad * 8;
#pragma unroll
        for (int p = 0; p < 2; ++p) {
            Ah[p] = *(const bf16x8*)(Khi  + base + p * 16 * ICP1);
            Am[p] = *(const bf16x8*)(Kmid + base + p * 16 * ICP1);
            Al[p] = *(const bf16x8*)(Klo  + base + p * 16 * ICP1);
        }
    };

    auto step = [&](int n, bf16x8* Ah, bf16x8* Am, bf16x8* Al) {
        const int j = n / 5;
        const int ic = n - 5 * j;
        int r0 = lm + j - 10;          r0 = ((unsigned)r0 < 25u) ? r0 : 25;
        int r1 = 16 + lm + j - 10;     r1 = ((unsigned)r1 < 25u) ? r1 : 25;
        const int col = ic * 32 + quad * 8;
#pragma unroll
        for (int bl = 0; bl < 2; ++bl) {
            bf16x8 Bh[2], Bm[2], Bl[2];
#pragma unroll
            for (int th = 0; th < 2; ++th) {
                const int row = th ? r1 : r0;
                const int ofs = bl * XSZ1 + row * XC1 + col;
                Bh[th] = *(const bf16x8*)&xs[0 * SS1 + ofs];
                Bm[th] = *(const bf16x8*)&xs[1 * SS1 + ofs];
                Bl[th] = *(const bf16x8*)&xs[2 * SS1 + ofs];
            }
#pragma unroll
            for (int p = 0; p < 2; ++p)
#pragma unroll
                for (int th = 0; th < 2; ++th)
                    acc[p][bl * 2 + th] = MFMA16(Ah[p], Bh[th], acc[p][bl * 2 + th]);
#pragma unroll
            for (int p = 0; p < 2; ++p)
#pragma unroll
                for (int th = 0; th < 2; ++th)
                    acc[p][bl * 2 + th] = MFMA16(Ah[p], Bm[th], acc[p][bl * 2 + th]);
#pragma unroll
            for (int p = 0; p < 2; ++p)
#pragma unroll
                for (int th = 0; th < 2; ++th)
                    acc[p][bl * 2 + th] = MFMA16(Am[p], Bh[th], acc[p][bl * 2 + th]);
#pragma unroll
            for (int p = 0; p < 2; ++p)
#pragma unroll
                for (int th = 0; th < 2; ++th)
                    acc[p][bl * 2 + th] = MFMA16(Ah[p], Bl[th], acc[p][bl * 2 + th]);
#pragma unroll
            for (int p = 0; p < 2; ++p)
#pragma unroll
                for (int th = 0; th < 2; ++th)
                    acc[p][bl * 2 + th] = MFMA16(Am[p], Bm[th], acc[p][bl * 2 + th]);
#pragma unroll
            for (int p = 0; p < 2; ++p)
#pragma unroll
                for (int th = 0; th < 2; ++th)
                    acc[p][bl * 2 + th] = MFMA16(Al[p], Bh[th], acc[p][bl * 2 + th]);
        }
    };

    bf16x8 A0h[2], A0m[2], A0l[2], A1h[2], A1m[2], A1l[2];
    loadA(0, A0h, A0m, A0l);
    for (int n = 0; n < 54; n += 2) {
        loadA(n + 1, A1h, A1m, A1l);
        step(n, A0h, A0m, A0l);
        loadA(n + 2, A0h, A0m, A0l);
        step(n + 1, A1h, A1m, A1l);
    }
    step(54, A0h, A0m, A0l);

#pragma unroll
    for (int bl = 0; bl < 2; ++bl) {
        __syncthreads();
#pragma unroll
        for (int p = 0; p < 2; ++p)
#pragma unroll
            for (int th = 0; th < 2; ++th) {
                int t = th * 16 + lm;
                if (t < TT) {
                    int ob = w * 32 + p * 16 + quad * 4;
#pragma unroll
                    for (int v = 0; v < 4; ++v)
                        ys[(ob + v) * 27 + t] = acc[p][bl * 2 + th][v];
                }
            }
        __syncthreads();
        if (tid < 256) {
            const int o = tid;
            float scale = gamma[o] / sqrtf(var[o] + 1e-5f);
            float ofs   = (bias[o] - mean[o]) * scale + beta[o];
            unsigned short* dst =
                (unsigned short*)spk1 + (size_t)(b0 + bl) * (TT * 256) + o;
            const float* yrow = &ys[o * 27];
            float memv = 0.f;
#pragma unroll
            for (int t = 0; t < TT; ++t) {
                float a     = yrow[t] * scale + ofs;
                float reset = (memv > 1.0f) ? 1.0f : 0.f;
                memv        = 0.95f * memv + a - reset;
                dst[t * 256] = (memv > 1.0f) ? 0x3F80 : 0;
            }
        }
    }
}

// ---------------------------------------------------------------------------
// Layer 2 — v10: halve A-bytes/MFMA. r9 analysis: conv2 was capped at ~53%
// of MFMA floor by L2 A-delivery RATE (128 B/MFMA demand = 105 B/cy/CU vs
// 56 available). Fix: 8 batches/block -> 16 N-frags per A-load -> 64 B/MFMA
// (demand 52.8 B/cy <= 56). Needs acc[2][16] = 128 VGPR, so run in the
// 2-waves/SIMD 256-VGPR regime: grid 256 (1 block/CU), 512 threads, 8 waves
// = 4 ch-tiles (32 ch, pi=2) x 2 kg (44 K-steps each). The 256-reg budget
// restores TRUE A ping-pong (r4's failure was 88-reg JIT-A latency at this
// occupancy): 96 MFMA = 466 cy compute >> ~300 cy L2 latency -> ILP hides.
// Gap-8 acc rotation (r9 win). XCD-parity channel half: per-XCD A-set
// 2.16 MB L2-resident. LDS 123136 B. kg partials via ysq[2][64][26].
// ---------------------------------------------------------------------------
__attribute__((amdgpu_waves_per_eu(2, 2)))
__global__ __launch_bounds__(512)
void conv2_mfma(const __bf16* __restrict__ spk1,
                const __bf16* __restrict__ Khi,   // [j][256][256]
                const __bf16* __restrict__ Kmid,
                const __bf16* __restrict__ Klo,
                const float* __restrict__ bias,
                const float* __restrict__ gamma,
                const float* __restrict__ beta,
                const float* __restrict__ mean,
                const float* __restrict__ var,
                __bf16* __restrict__ spk2) {
    __shared__ __align__(16) char smem[123136];
    __bf16* xs  = (__bf16*)smem;                 // [8][26][264] = 109824 B
    float*  ysq = (float*)(smem + 109824);       // [2][64][26]  = 13312 B

    const int h    = blockIdx.x & 1;             // channel half (XCD-parity)
    const int bg   = blockIdx.x >> 1;            // batch group (8 batches)
    const int b0   = bg * 8;
    const int oc0  = h * 128;

    const int tid  = threadIdx.x;
    const int w    = tid >> 6;                   // 0..7
    const int wc   = w & 3;                      // channel tile (32 ch)
    const int kg   = w >> 2;                     // K-group 0/1
    const int lane = tid & 63;
    const int lm   = lane & 15;
    const int quad = lane >> 4;

    for (int k = tid; k < 8 * (XC / 2); k += 512) {
        int bl = k / (XC / 2);
        int c  = k % (XC / 2);
        ((uint32_t*)xs)[(bl * XSZ2 + 25 * XC) / 2 + c] = 0u;
    }
    for (int k = tid; k < 8 * 800; k += 512) {
        int bl = k / 800;
        int v  = k % 800;
        int t  = v >> 5;
        int iv = v & 31;
        uint4 d = ((const uint4*)(spk1 + (size_t)(b0 + bl) * (TT * 256)))[v];
        *(uint4*)&xs[bl * XSZ2 + t * XC + iv * 8] = d;
    }
    __syncthreads();

    f32x4 acc[2][16];   // [pi][bl*2+th], bl = 0..7
#pragma unroll
    for (int pi = 0; pi < 2; ++pi)
#pragma unroll
        for (int nt = 0; nt < 16; ++nt) acc[pi][nt] = (f32x4){0.f, 0.f, 0.f, 0.f};

    {
        const int n0 = kg * 44;
        // A order: [0]=Ah0 [1]=Ah1 [2]=Am0 [3]=Am1 [4]=Al0 [5]=Al1
        auto loadA = [&](int n, bf16x8* A) {
            const int j = n >> 3, ic = n & 7;
            const size_t base =
                (size_t)(j * 256 + oc0 + wc * 32 + lm) * 256 + ic * 32 + quad * 8;
            A[0] = *(const bf16x8*)(Khi  + base);
            A[1] = *(const bf16x8*)(Khi  + base + 16 * 256);
            A[2] = *(const bf16x8*)(Kmid + base);
            A[3] = *(const bf16x8*)(Kmid + base + 16 * 256);
            A[4] = *(const bf16x8*)(Klo  + base);
            A[5] = *(const bf16x8*)(Klo  + base + 16 * 256);
        };
        auto step = [&](int n, const bf16x8* A) {
            const int j = n >> 3, ic = n & 7;
            int r0 = lm + j - 10;          r0 = ((unsigned)r0 < 25u) ? r0 : 25;
            int r1 = 16 + lm + j - 10;     r1 = ((unsigned)r1 < 25u) ? r1 : 25;
            const int col = ic * 32 + quad * 8;
#pragma unroll
            for (int bp = 0; bp < 4; ++bp) {
                const int blA = bp * 2, blB = bp * 2 + 1;
                bf16x8 B0A = *(const bf16x8*)&xs[blA * XSZ2 + r0 * XC + col];
                bf16x8 B1A = *(const bf16x8*)&xs[blA * XSZ2 + r1 * XC + col];
                bf16x8 B0B = *(const bf16x8*)&xs[blB * XSZ2 + r0 * XC + col];
                bf16x8 B1B = *(const bf16x8*)&xs[blB * XSZ2 + r1 * XC + col];
                const int a0 = blA * 2, a1 = blA * 2 + 1;
                const int a2 = blB * 2, a3 = blB * 2 + 1;
#pragma unroll
                for (int s = 0; s < 3; ++s) {
                    // rotate all 8 live accs before reuse: same-acc gap = 8
                    acc[0][a0] = MFMA16(A[s * 2 + 0], B0A, acc[0][a0]);
                    acc[1][a0] = MFMA16(A[s * 2 + 1], B0A, acc[1][a0]);
                    acc[0][a1] = MFMA16(A[s * 2 + 0], B1A, acc[0][a1]);
                    acc[1][a1] = MFMA16(A[s * 2 + 1], B1A, acc[1][a1]);
                    acc[0][a2] = MFMA16(A[s * 2 + 0], B0B, acc[0][a2]);
                    acc[1][a2] = MFMA16(A[s * 2 + 1], B0B, acc[1][a2]);
                    acc[0][a3] = MFMA16(A[s * 2 + 0], B1B, acc[0][a3]);
                    acc[1][a3] = MFMA16(A[s * 2 + 1], B1B, acc[1][a3]);
                }
            }
        };

        bf16x8 A0[6], A1[6];
        loadA(n0, A0);
        for (int n = n0; n < n0 + 42; n += 2) {
            loadA(n + 1, A1);
            step(n, A0);
            loadA(n + 2, A0);
            step(n + 1, A1);
        }
        loadA(n0 + 43, A1);
        step(n0 + 42, A0);
        step(n0 + 43, A1);
    }

    // ------- epilogue: combine K-groups, BN + LIF, spikes to global -------
    // 64-ch chunk q of this block's 128: owner waves wc in {2q,2q+1}, both kg.
#pragma unroll
    for (int bl = 0; bl < 8; ++bl) {
#pragma unroll
        for (int q = 0; q < 2; ++q) {
            __syncthreads();
            if ((wc >> 1) == q) {
#pragma unroll
                for (int pi = 0; pi < 2; ++pi)
#pragma unroll
                    for (int th = 0; th < 2; ++th) {
                        int t = th * 16 + lm;
                        if (t < TT) {
                            int ol = (wc & 1) * 32 + pi * 16 + quad * 4;
#pragma unroll
                            for (int v = 0; v < 4; ++v)
                                ysq[(kg * 64 + ol + v) * 26 + t] =
                                    acc[pi][bl * 2 + th][v];
                        }
                    }
            }
            __syncthreads();
            if (tid < 64) {
                const int o = oc0 + q * 64 + tid;
                float scale = gamma[o] / sqrtf(var[o] + 1e-5f);
                float ofs   = (bias[o] - mean[o]) * scale + beta[o];
                const float* yr0 = &ysq[tid * 26];
                const float* yr1 = &ysq[(64 + tid) * 26];
                unsigned short* dst =
                    (unsigned short*)spk2 + (size_t)(b0 + bl) * (TT * 256) + o;
                float memv = 0.f;
#pragma unroll
                for (int t = 0; t < TT; ++t) {
                    float a     = (yr0[t] + yr1[t]) * scale + ofs;
                    float reset = (memv > 1.0f) ? 1.0f : 0.f;
                    memv        = 0.95f * memv + a - reset;
                    dst[t * 256] = (memv > 1.0f) ? 0x3F80 : 0;
                }
            }
        }
    }
}

// ---------------------------------------------------------------------------
// Layer 3 + LIF3: staging spk2 from global (A3 = 528 KB, L2-resident).
// Grid 256 x 4 batches, 512 threads. Verbatim from r4.
// ---------------------------------------------------------------------------
__global__ __launch_bounds__(512, 2)
void conv3_mfma(const __bf16* __restrict__ spk2,
                const __bf16* __restrict__ K3hi,   // [j][32][256]
                const __bf16* __restrict__ K3mid,
                const __bf16* __restrict__ K3lo,
                const float* __restrict__ b3,
                float* __restrict__ out) {
    __shared__ __align__(16) char smem[54912];
    __bf16* xs  = (__bf16*)smem;                 // [4][26][264] = 54912 B
    float*  ys3 = (float*)smem;                  // [4][32][26] alias (after)

    const int b0   = blockIdx.x * 4;
    const int tid  = threadIdx.x;
    const int w    = tid >> 6;                   // 0..7
    const int lane = tid & 63;
    const int lm   = lane & 15;
    const int quad = lane >> 4;

    for (int k = tid; k < 4 * (XC / 2); k += 512) {
        int bl = k / (XC / 2);
        int c  = k % (XC / 2);
        ((uint32_t*)xs)[(bl * XSZ2 + 25 * XC) / 2 + c] = 0u;
    }
    for (int k = tid; k < 4 * 800; k += 512) {
        int bl = k / 800;
        int v  = k % 800;
        int t  = v >> 5;
        int iv = v & 31;
        uint4 d = ((const uint4*)(spk2 + (size_t)(b0 + bl) * (TT * 256)))[v];
        *(uint4*)&xs[bl * XSZ2 + t * XC + iv * 8] = d;
    }
    __syncthreads();

    {
        const int p3  = w >> 2;      // o3-tile (0..1)
        const int bl3 = w & 3;       // batch (0..3)
        f32x4 accH[2], accM[2], accL[2];   // [th]
#pragma unroll
        for (int th = 0; th < 2; ++th) {
            accH[th] = (f32x4){0.f, 0.f, 0.f, 0.f};
            accM[th] = (f32x4){0.f, 0.f, 0.f, 0.f};
            accL[th] = (f32x4){0.f, 0.f, 0.f, 0.f};
        }

        auto loadA3 = [&](int n, bf16x8* Ah, bf16x8* Am, bf16x8* Al) {
            n = (n > 87) ? 87 : n;
            const int j = n >> 3, ic = n & 7;
            const size_t kofs =
                ((size_t)(j * 32 + p3 * 16 + lm)) * 256 + ic * 32 + quad * 8;
            *Ah = *(const bf16x8*)(K3hi  + kofs);
            *Am = *(const bf16x8*)(K3mid + kofs);
            *Al = *(const bf16x8*)(K3lo  + kofs);
        };
        auto step3 = [&](int n, bf16x8 Ah, bf16x8 Am, bf16x8 Al) {
            const int j = n >> 3, ic = n & 7;
#pragma unroll
            for (int th = 0; th < 2; ++th) {
                int r = th * 16 + lm + j - 10;
                r = ((unsigned)r < 25u) ? r : 25;
                bf16x8 Bf =
                    *(const bf16x8*)&xs[bl3 * XSZ2 + r * XC + ic * 32 + quad * 8];
                accH[th] = MFMA16(Ah, Bf, accH[th]);
                accM[th] = MFMA16(Am, Bf, accM[th]);
                accL[th] = MFMA16(Al, Bf, accL[th]);
            }
        };

        bf16x8 A0h, A0m, A0l, A1h, A1m, A1l;
        loadA3(0, &A0h, &A0m, &A0l);
        for (int n = 0; n < 86; n += 2) {
            loadA3(n + 1, &A1h, &A1m, &A1l);
            step3(n, A0h, A0m, A0l);
            loadA3(n + 2, &A0h, &A0m, &A0l);
            step3(n + 1, A1h, A1m, A1l);
        }
        loadA3(87, &A1h, &A1m, &A1l);
        step3(86, A0h, A0m, A0l);
        step3(87, A1h, A1m, A1l);

        __syncthreads();   // xs dead; reuse smem as ys3
#pragma unroll
        for (int th = 0; th < 2; ++th) {
            int t = th * 16 + lm;
            if (t < TT) {
#pragma unroll
                for (int v = 0; v < 4; ++v)
                    ys3[(bl3 * 32 + p3 * 16 + quad * 4 + v) * 26 + t] =
                        accH[th][v] + accM[th][v] + accL[th][v];
            }
        }
        __syncthreads();

        if (tid < 80) {
            const int bl2 = tid / 20;
            const int o   = tid % 20;
            float memv = 0.f;
            float bo   = b3[o];
            const float* yrow = &ys3[(bl2 * 32 + o) * 26];
#pragma unroll
            for (int t = 0; t < TT; ++t) {
                float a     = yrow[t] + bo;
                float reset = (memv > 1.0f) ? 1.0f : 0.f;
                memv        = 0.95f * memv + a - reset;
                float spk   = (memv > 1.0f) ? 1.0f : 0.f;
                out[(t * BB + (b0 + bl2)) * 20 + o]               = spk;
                out[TT * BB * 20 + (t * BB + (b0 + bl2)) * 20 + o] = memv;
            }
        }
    }
}

// ---------------------------------------------------------------------------
extern "C" void kernel_launch(void* const* d_in, const int* in_sizes, int n_in,
                              void* d_out, int out_size, void* d_ws, size_t ws_size,
                              hipStream_t stream) {
    const float* data = (const float*)d_in[0];
    const float* W1   = (const float*)d_in[1];
    const float* b1   = (const float*)d_in[2];
    const float* P1   = (const float*)d_in[3];
    const float* SIG1 = (const float*)d_in[4];
    const float* g1   = (const float*)d_in[5];
    const float* be1  = (const float*)d_in[6];
    const float* m1   = (const float*)d_in[7];
    const float* v1   = (const float*)d_in[8];
    const float* W2   = (const float*)d_in[9];
    const float* b2   = (const float*)d_in[10];
    const float* P2   = (const float*)d_in[11];
    const float* SIG2 = (const float*)d_in[12];
    const float* g2   = (const float*)d_in[13];
    const float* be2  = (const float*)d_in[14];
    const float* m2   = (const float*)d_in[15];
    const float* v2   = (const float*)d_in[16];
    const float* W3   = (const float*)d_in[17];
    const float* b3   = (const float*)d_in[18];
    const float* P3   = (const float*)d_in[19];
    const float* SIG3 = (const float*)d_in[20];
    float* out = (float*)d_out;

    // workspace layout (byte offsets, all 16B-aligned)
    char* p = (char*)d_ws;
    __bf16* K1hi  = (__bf16*)p;  p += 901120;    // 11*256*160 bf16
    __bf16* K1mid = (__bf16*)p;  p += 901120;
    __bf16* K1lo  = (__bf16*)p;  p += 901120;
    __bf16* spk1  = (__bf16*)p;  p += 13107200;  // 1024*25*256 bf16
    __bf16* K2hi  = (__bf16*)p;  p += 1441792;   // 11*256*256 bf16
    __bf16* K2mid = (__bf16*)p;  p += 1441792;
    __bf16* K2lo  = (__bf16*)p;  p += 1441792;
    __bf16* K3hi  = (__bf16*)p;  p += 180224;    // 11*32*256 bf16
    __bf16* K3mid = (__bf16*)p;  p += 180224;
    __bf16* K3lo  = (__bf16*)p;  p += 180224;
    __bf16* spk2  = (__bf16*)p;                  // 1024*25*256 bf16 = 13107200

    gen_trip<<<(256 * 160 + 255) / 256, 256, 0, stream>>>(
        W1, P1, SIG1, K1hi, K1mid, K1lo, 256, 256, 140, 160);
    gen_trip<<<(256 * 256 + 255) / 256, 256, 0, stream>>>(
        W2, P2, SIG2, K2hi, K2mid, K2lo, 256, 256, 256, 256);
    gen_trip<<<(32 * 256 + 255) / 256, 256, 0, stream>>>(
        W3, P3, SIG3, K3hi, K3mid, K3lo, 20, 32, 256, 256);

    conv1_mfma<<<BB / 2, 512, 0, stream>>>(data, K1hi, K1mid, K1lo,
                                           b1, g1, be1, m1, v1, spk1);
    conv2_mfma<<<BB / 4, 512, 0, stream>>>(spk1, K2hi, K2mid, K2lo,
                                           b2, g2, be2, m2, v2, spk2);
    conv3_mfma<<<BB / 4, 512, 0, stream>>>(spk2, K3hi, K3mid, K3lo, b3, out);
}